// Round 1
// baseline (1697.429 us; speedup 1.0000x reference)
//
#include <hip/hip_runtime.h>

// Top2Gate: N=65536 rows, D=2048 features, K=64 experts, fp32.
// out = [top2_probs (N*K) | entropy (N) | logits (N*K)]  (float32, concat)
//
// Structure: one thread per (row, D-half). acc[64] logits in VGPRs.
// W addresses are wave-uniform -> scalar loads (s_load) through scalar cache.
// Wave-pairs 0/1 do D[0:1024), wave-pairs 2/3 do D[1024:2048); merge via LDS.
// 512 blocks x 256 threads = 2 waves/SIMD for latency hiding.

#define NN 65536
#define DD 2048
#define KK 64

__global__ __launch_bounds__(256, 2) void top2gate_kernel(
    const float* __restrict__ x, const float* __restrict__ W,
    const float* __restrict__ b, float* __restrict__ out) {
  // +1 pad -> (r*65+k)%32 = (r+k)%32: consecutive lanes hit consecutive banks
  __shared__ float lacc[128][KK + 1];

  const int tid = threadIdx.x;
  // Wave-uniform by construction (tid>>7 constant across each 64-lane wave);
  // readfirstlane makes the compiler's uniformity analysis see it, so W
  // addresses stay scalar (s_load) instead of falling to vector loads.
  const int half = __builtin_amdgcn_readfirstlane(tid >> 7);
  const int r = tid & 127;
  const size_t n = (size_t)blockIdx.x * 128 + r;

  float acc[KK];
#pragma unroll
  for (int k = 0; k < KK; ++k) acc[k] = 0.f;

  const float4* __restrict__ xrow = (const float4*)(x + n * DD);
  const int d4base = half * (DD / 8);  // float4 index; DD/8 = 256 float4 per half
  for (int d4 = d4base; d4 < d4base + DD / 8; ++d4) {
    const float4 xv = xrow[d4];
#pragma unroll
    for (int k = 0; k < KK; ++k) {
      const float4 wv = *(const float4*)(W + (size_t)k * DD + 4 * (size_t)d4);
      acc[k] = fmaf(xv.x, wv.x, acc[k]);
      acc[k] = fmaf(xv.y, wv.y, acc[k]);
      acc[k] = fmaf(xv.z, wv.z, acc[k]);
      acc[k] = fmaf(xv.w, wv.w, acc[k]);
    }
  }

  if (half == 1) {
#pragma unroll
    for (int k = 0; k < KK; ++k) lacc[r][k] = acc[k];
  }
  __syncthreads();
  if (half == 1) return;  // no further barriers; upper half done

#pragma unroll
  for (int k = 0; k < KK; ++k) acc[k] += lacc[r][k] + b[k];
  // TEMPERATURE == 1.0 -> logits = acc as-is

  // ---- epilogue: softmax + top-2 + renorm + entropy (all per-thread) ----
  float mx = acc[0];
#pragma unroll
  for (int k = 1; k < KK; ++k) mx = fmaxf(mx, acc[k]);

  float ssum = 0.f;
#pragma unroll
  for (int k = 0; k < KK; ++k) ssum += __expf(acc[k] - mx);

  // top-2 over logits (== top-2 over probs; strict '>' keeps lowest index on
  // ties, matching jax.lax.top_k)
  float v1 = -3.0e38f, v2 = -3.0e38f;
  int i1 = 0, i2 = 0;
#pragma unroll
  for (int k = 0; k < KK; ++k) {
    const float v = acc[k];
    if (v > v1) {
      v2 = v1; i2 = i1; v1 = v; i1 = k;
    } else if (v > v2) {
      v2 = v; i2 = k;
    }
  }

  const float p1 = __expf(v1 - mx) / ssum;
  const float p2 = __expf(v2 - mx) / ssum;
  const float denom = p1 + p2 + 1e-9f;  // reference's exact renorm epsilon
  const float t1 = p1 / denom;
  const float t2 = p2 / denom;
  const float ent = -(t1 * __logf(fmaxf(t1, 1e-12f)) +
                      t2 * __logf(fmaxf(t2, 1e-12f)));

  // ---- writes (every output element is written; d_out is poisoned) ----
  float* __restrict__ probs_out = out + n * KK;
  float* __restrict__ ent_out = out + (size_t)NN * KK;
  float* __restrict__ log_out = out + (size_t)NN * KK + NN + n * KK;

#pragma unroll
  for (int k = 0; k < KK; ++k) log_out[k] = acc[k];
#pragma unroll
  for (int k = 0; k < KK; ++k) {
    probs_out[k] = (k == i1) ? t1 : ((k == i2) ? t2 : 0.f);
  }
  ent_out[n] = ent;
}

extern "C" void kernel_launch(void* const* d_in, const int* in_sizes, int n_in,
                              void* d_out, int out_size, void* d_ws,
                              size_t ws_size, hipStream_t stream) {
  const float* x = (const float*)d_in[0];
  const float* W = (const float*)d_in[1];
  const float* b = (const float*)d_in[2];
  float* out = (float*)d_out;

  dim3 grid(NN / 128);
  dim3 block(256);
  hipLaunchKernelGGL(top2gate_kernel, grid, block, 0, stream, x, W, b, out);
}